// Round 10
// baseline (106.344 us; speedup 1.0000x reference)
//
#include <hip/hip_runtime.h>
#include <stdint.h>

// Match numpy semantics: no FMA contraction anywhere in decision-critical math.
#pragma clang fp contract(off)

#define N_ANCHORS 172032  // compile-time problem constant
#define MAX_OUT 200
#define BLK 1024
#define GRID 168          // GRID*BLK == N_ANCHORS exactly
#define NW (BLK / 64)     // 16 waves
#define SEG 32            // per-block segment capacity (lambda~8.4 @VT=2.40; guarded)
#define NKEY (GRID * SEG) // 5376 — compact-key capacity
#define RMAX 1024         // suppression-matrix rank capacity. Correctness is
                          // guaranteed VT/RMAX-independent: if the true greedy's
                          // next pick lies outside the rank window, the windowed
                          // alive set is empty at that point -> ln<200 -> exact
                          // fallback. rank_200 < 900 (round-5 evidence) makes the
                          // fast path overwhelmingly likely.
#define MASKW (RMAX / 64) // 16 ull words per row
#define RCAND 64          // candidates ranked per k_rank block (emitted by wave 0)
#define RGRID (NKEY / RCAND) // 84 rank blocks (only ~csel/64 ~ 22 stay active)
#define RBLK 1024         // k_rank block size: 16 waves split the j-range
#define RW (RBLK / 64)    // 16 waves
#define MGRID 128         // k_mask blocks (8 IoU-words per wave)
#define VT 2.40f          // fixed prefix threshold: scores ~ N(0,1) =>
                          // csel ~ 1411 +/- 37 (>10 sigma above RMAX=1024, so
                          // top-1024-above-VT == top-1024-above-0.4).
                          // Inline exact fallback guards all tails.

typedef unsigned long long ull;
static_assert(GRID * BLK == N_ANCHORS, "grid covers anchors exactly");
static_assert(RMAX % 64 == 0, "mask words");
static_assert(RGRID * RCAND == NKEY, "rank grid covers key capacity");
static_assert(GRID <= 192, "prefix scan uses 3 waves");

// f64 decode: f32 inputs upcast to f64, reference op order. Returns (y1,x1,y2,x2).
__device__ __forceinline__ void decode_box_d(const float4* __restrict__ reg,
                                             const float4* __restrict__ anc, int i,
                                             double b[4]) {
#pragma clang fp contract(off)
    float4 r = reg[i];
    float4 a = anc[i];
    double dx = (double)r.x * 0.1;
    double dy = (double)r.y * 0.1;
    double dw = (double)r.z * 0.2;
    double dh = (double)r.w * 0.2;
    double xa = (double)a.x, ya = (double)a.y, wa = (double)a.z, ha = (double)a.w;
    double xc = dx * wa; xc = xc + xa;     // dx*w_a + x_a
    double yc = dy * ha; yc = yc + ya;     // dy*h_a + y_a
    double w = exp(dw) * wa;
    double h = exp(dh) * ha;
    double h2 = h * 0.5, w2 = w * 0.5;
    b[0] = yc - h2; b[1] = xc - w2; b[2] = yc + h2; b[3] = xc + w2;
}

// One quarter of an output row: part 0 = box float4; parts 1..3 = landmark pairs
// {0,1},{2,3},{4}. Arithmetic per field identical to prior validated write_row
// (rounds 4-9, absmax 0.0); split across 4 threads/row to cut the scattered-
// gather latency chain.
__device__ __forceinline__ void write_row_part(const float4* __restrict__ reg,
                                               const float4* __restrict__ anc,
                                               const float* __restrict__ lnd,
                                               int q, int part, int idx,
                                               float* __restrict__ out) {
#pragma clang fp contract(off)
    if (part == 0) {
        float4 bv = make_float4(0.f, 0.f, 0.f, 0.f);
        if (idx >= 0) {
            double bb[4];
            decode_box_d(reg, anc, idx, bb);
            bv = make_float4((float)bb[0], (float)bb[1], (float)bb[2], (float)bb[3]);
        }
        *(float4*)&out[q * 4] = bv;                        // 16B-aligned
        return;
    }
    int j0 = (part - 1) * 2;               // part 1 -> j0=0 (2 pairs); 2 -> 2; 3 -> 4 (1)
    int nj = (part == 3) ? 1 : 2;
    float2 lv[2] = {make_float2(0.f, 0.f), make_float2(0.f, 0.f)};
    if (idx >= 0) {
        float4 a = anc[idx];
        double xa = (double)a.x, ya = (double)a.y, wa = (double)a.z, ha = (double)a.w;
        const float2* l2p = (const float2*)lnd;            // (N,10) f32, 8B-aligned
        for (int k = 0; k < nj; ++k) {
            float2 lp = l2p[idx * 5 + j0 + k];
            double lx = (double)lp.x * 0.1;
            double ly = (double)lp.y * 0.1;
            lx = lx * wa; lx = lx + xa;
            ly = ly * ha; ly = ly + ya;
            lv[k] = make_float2((float)lx, (float)ly);
        }
    }
    float2* o2 = (float2*)&out[MAX_OUT * 4 + q * 10];      // 8B-aligned (800+10q even)
    for (int k = 0; k < nj; ++k) o2[j0 + k] = lv[k];
}

__device__ __forceinline__ ull wmax(ull k) {
    for (int d = 32; d > 0; d >>= 1) {
        ull o = __shfl_down(k, d, 64);
        if (o > k) k = o;
    }
    return k;
}

// uniform-lane 64-bit readlane (SGPR broadcast path — no ds_bpermute latency)
__device__ __forceinline__ ull readlane64(ull v, int l) {
    unsigned lo = (unsigned)__builtin_amdgcn_readlane((int)(unsigned)(v & 0xffffffffull), l);
    unsigned hi = (unsigned)__builtin_amdgcn_readlane((int)(unsigned)(v >> 32), l);
    return ((ull)hi << 32) | (ull)lo;
}

// 64-bit shfl_xor (two 32-bit halves)
__device__ __forceinline__ ull shflx64(ull v, int m) {
    int lo = __shfl_xor((int)(unsigned)(v & 0xffffffffull), m, 64);
    int hi = __shfl_xor((int)(unsigned)(v >> 32), m, 64);
    return ((ull)(unsigned)hi << 32) | (ull)(unsigned)lo;
}

// f64 IoU > 0.4 test, reference op order (validated in prior rounds).
__device__ __forceinline__ bool iou_gt_f4(float4 a, float4 p) {
#pragma clang fp contract(off)
    double y1 = (double)a.x, x1 = (double)a.y, y2 = (double)a.z, x2 = (double)a.w;
    double p0 = (double)p.x, p1 = (double)p.y, p2 = (double)p.z, p3 = (double)p.w;
    double ih = fmin(y2, p2) - fmax(y1, p0); ih = fmax(ih, 0.0);
    double iw = fmin(x2, p3) - fmax(x1, p1); iw = fmax(iw, 0.0);
    double inter = ih * iw;
    double aj = (y2 - y1) * (x2 - x1);
    double ap = (p2 - p0) * (p3 - p1);
    double den = aj + ap; den = den - inter; den = den + 1e-12;
    return (inter / den) > 0.4;
}

// ---------- kernel 1: segment compaction (no atomics, no memset needed) ----------
__global__ void __launch_bounds__(BLK) k_seg(const float2* __restrict__ cls,
                                             int* __restrict__ segcnt,
                                             ull* __restrict__ segkeys) {
    __shared__ int wcnt[NW];
    int tid = threadIdx.x, bid = blockIdx.x;
    int i = bid * BLK + tid;
    float sc = cls[i].y;                   // score = cls[:,1]
    bool c = (sc > VT);
    ull key = 0ull;
    if (c) key = ((ull)__float_as_uint(sc) << 32)
               | (ull)(0xFFFFFFFFu - (unsigned int)i);
    ull m = __ballot(c);
    int wid = tid >> 6, lane = tid & 63;
    if (lane == 0) wcnt[wid] = __popcll(m);
    __syncthreads();
    if (tid == 0) {
        int s = 0;
        for (int w = 0; w < NW; ++w) { int t = wcnt[w]; wcnt[w] = s; s += t; }
        segcnt[bid] = s;                   // unconditional (overflow detected downstream)
    }
    __syncthreads();
    if (c) {
        int pos = wcnt[wid] + __popcll(m & ((1ull << lane) - 1ull));
        if (pos < SEG) segkeys[bid * SEG + pos] = key;
    }
}

// emit one ranked candidate: idx + decoded box in rank order
__device__ __forceinline__ void rank_emit(const float4* __restrict__ reg,
                                          const float4* __restrict__ anc,
                                          int rank, ull key,
                                          int* __restrict__ gidx,
                                          float4* __restrict__ gbox) {
    int idx = (int)(0xFFFFFFFFu - (unsigned int)key);
    gidx[rank] = idx;
    double b[4];
    decode_box_d(reg, anc, idx, b);
    gbox[rank] = make_float4((float)b[0], (float)b[1], (float)b[2], (float)b[3]);
}

// ---------- kernel 2: PARALLEL rank-counting sort (84 blocks x 16 waves) ----------
// rank = #keys strictly greater (keys unique) => value-based, block order irrelevant.
// NOTE (round-10 post-mortem of r1): candidate distribution across blocks is
// essential — per-block LDS broadcast reads scale as waves x csel, so full-rank
// per block would cost ~csel^2/64 reads ~ 55us. Do not merge this into k_mask.
__global__ void __launch_bounds__(RBLK) k_rank(const float4* __restrict__ reg,
                                               const float4* __restrict__ anc,
                                               const int* __restrict__ segcnt,
                                               const ull* __restrict__ segkeys,
                                               int* __restrict__ meta,
                                               int* __restrict__ gidx,
                                               float4* __restrict__ gbox) {
    __shared__ ull skeys[NKEY];            // 43 KB
    __shared__ int scnt[GRID], spre[GRID];
    __shared__ int wsum[4];
    __shared__ ull wovf[4];
    __shared__ int spart[RBLK];            // per-wave partial ranks (4 KB)
    __shared__ int s_ok, s_csel;
    int tid = threadIdx.x, wid = tid >> 6, lane = tid & 63;

    // (a) parallel prefix over segment counts (GRID=168 -> waves 0..2)
    int v = 0; bool ovf = false;
    if (tid < GRID) { v = segcnt[tid]; scnt[tid] = v; ovf = (v > SEG); }
    int x = v;
    for (int d = 1; d < 64; d <<= 1) {
        int o = __shfl_up(x, d, 64);
        if (lane >= d) x += o;
    }
    ull om = __ballot(ovf);
    if (wid < 3 && lane == 63) { wsum[wid] = x; wovf[wid] = om; }
    __syncthreads();
    if (tid == 0) {
        int total = wsum[0] + wsum[1] + wsum[2];
        s_csel = total;
        s_ok = ((wovf[0] | wovf[1] | wovf[2]) == 0ull) ? 1 : 0;
        if (blockIdx.x == 0) { meta[0] = s_ok; meta[1] = total; }
    }
    __syncthreads();
    if (tid < GRID)
        spre[tid] = (x - v) + (wid >= 1 ? wsum[0] : 0) + (wid >= 2 ? wsum[1] : 0);
    bool okl = (s_ok != 0);
    int csel = s_csel;
    int cbase = blockIdx.x * RCAND;
    __syncthreads();                       // spre visible to all
    if (!okl) return;                      // uniform -> exact fallback in k_pick
    if (cbase >= csel) return;             // inactive tail blocks exit (uniform)

    // (b) stage dense keys (predicated scatter from padded segkeys)
    for (int t = tid; t < GRID * SEG; t += RBLK) {
        int s = t >> 5, k = t & (SEG - 1);
        if (k < scnt[s]) skeys[spre[s] + k] = segkeys[t];
    }
    __syncthreads();

    // (c) 16-wave partial rank counting (broadcast LDS reads, unroll 8)
    int per = (csel + RW - 1) / RW;
    int jb = wid * per;
    int je = jb + per; if (je > csel) je = csel;
    int c = cbase + lane;
    ull kc = (c < csel) ? skeys[c] : 0ull;
    int rk = 0;
#pragma unroll 8
    for (int j = jb; j < je; ++j)
        rk += (skeys[j] > kc) ? 1 : 0;
    spart[wid * 64 + lane] = rk;
    __syncthreads();

    // (d) wave 0: combine partials, emit rank-ordered idx + decoded box
    if (tid < RCAND) {
        int cc = cbase + tid;
        if (cc < csel) {
            int r = 0;
#pragma unroll
            for (int w = 0; w < RW; ++w) r += spart[w * 64 + tid];
            if (r < RMAX) rank_emit(reg, anc, r, skeys[cc], gidx, gbox);
        }
    }
}

// ---------- kernel 3: suppression bitmatrix (128 blocks, ballot form) ----------
// gmask[r*16+w] bit e <=> iou(box[w*64+e], box[r]) > 0.4. Diagonal bit naturally
// set => pick removes itself, preserving reference self-suppression semantics
// (incl. degenerate zero-area repeat picks). Additionally emits gdiag[r] = the
// row's own-chunk word (w == r>>6), a compact 8 KB array so k_pick never needs
// the full 128 KB matrix staged. No atomics/fences: kernel-boundary ordering.
__global__ void __launch_bounds__(BLK) k_mask(const int* __restrict__ meta,
                                              const float4* __restrict__ gbox,
                                              ull* __restrict__ gmask,
                                              ull* __restrict__ gdiag) {
    __shared__ float4 cbox[RMAX];          // 16 KB
    if (meta[0] == 0) return;              // uniform
    int csel = meta[1];
    int rlim = csel < RMAX ? csel : RMAX;
    if (rlim <= 0) return;
    int tid = threadIdx.x, bid = blockIdx.x;
    int wid = tid >> 6, lane = tid & 63;
    for (int t = tid; t < rlim; t += BLK) cbox[t] = gbox[t];
    __syncthreads();
    int totw = rlim * MASKW;
    for (int w = bid * NW + wid; w < totw; w += MGRID * NW) {
        int row = w >> 4, word = w & (MASKW - 1);
        int col = (word << 6) + lane;
        bool hit = (col < rlim) && iou_gt_f4(cbox[col], cbox[row]);
        ull bits = __ballot(hit);
        if (lane == 0) {
            gmask[w] = bits;
            if (word == (row >> 6)) gdiag[row] = bits;  // own-chunk word
        }
    }
}

// ---------- kernel 4: chunked register greedy, NO matrix staging ----------
// FIND logic identical to rounds 7-9 (validated). Diag words come from one
// coalesced 512B gdiag read per chunk; APPLY reads picked rows (128 B
// contiguous, 8 in flight) straight from global gmask. gdiag rows >= rlim are
// unwritten garbage but alive-masked so never consumed.
__global__ void __launch_bounds__(BLK) k_pick(const float2* __restrict__ cls,
                                              const float4* __restrict__ reg,
                                              const float4* __restrict__ anc,
                                              const float* __restrict__ lnd,
                                              const int* __restrict__ meta,
                                              const int* __restrict__ gidx,
                                              const ull* __restrict__ gmask,
                                              const ull* __restrict__ gdiag,
                                              float* __restrict__ sbuf,
                                              float* __restrict__ out) {
    __shared__ int s_kept[MAX_OUT];
    __shared__ int s_ln;
    __shared__ ull warr[NW];               // fallback
    __shared__ ull s_win;
    __shared__ double s_pb[5];

    int tid = threadIdx.x;
    int lane = tid & 63;
    bool pre_ok = (meta[0] != 0);
    int csel = meta[1];
    int rlim = csel < RMAX ? csel : RMAX;
    int ln = 0;

    if (pre_ok) {
        if (tid < 64) {
            ull alive = 0ull;              // lane w owns rank word w (w < MASKW)
            if (lane < MASKW) {
                int lo = lane << 6;
                int n = rlim - lo;
                if (n >= 64) alive = ~0ull;
                else if (n > 0) alive = (1ull << n) - 1ull;
            }
            int lnl = 0;
            int nchunk = (rlim + 63) >> 6;
            int g = lane >> 4, w = lane & 15;
            for (int c = 0; c < nchunk && lnl < MAX_OUT; ++c) {
                ull aw = readlane64(alive, c);        // includes all prior suppression
                if (aw == 0ull) continue;
                ull diag = gdiag[(c << 6) + lane];    // coalesced 512B global read
                // FIND (registers only)
                ull cur = aw, pmask = 0ull;
                while (cur != 0ull && lnl < MAX_OUT) {
                    int b = __ffsll(cur) - 1;
                    if (lane == 0) s_kept[lnl] = (c << 6) + b;   // store RANK
                    lnl++;
                    pmask |= (1ull << b);
                    ull rowb = readlane64(diag, b);   // row b's intra-chunk bits
                    cur &= ~rowb;                     // self-bit naturally set (or not,
                                                      // for degenerate repeat picks)
                }
                if (lnl >= MAX_OUT) break;            // alive no longer needed
                // APPLY (8 rows in flight per iteration, global coalesced 128B rows)
                ull pm = pmask;
                ull supp0 = 0ull, supp1 = 0ull;
                while (pm != 0ull) {
                    int b0 = __ffsll(pm) - 1; pm &= pm - 1ull;
                    int b1 = b0, b2 = b0, b3 = b0, b4 = b0, b5 = b0, b6 = b0, b7 = b0;
                    if (pm) { b1 = __ffsll(pm) - 1; pm &= pm - 1ull; }
                    if (pm) { b2 = __ffsll(pm) - 1; pm &= pm - 1ull; }
                    if (pm) { b3 = __ffsll(pm) - 1; pm &= pm - 1ull; }
                    if (pm) { b4 = __ffsll(pm) - 1; pm &= pm - 1ull; }
                    if (pm) { b5 = __ffsll(pm) - 1; pm &= pm - 1ull; }
                    if (pm) { b6 = __ffsll(pm) - 1; pm &= pm - 1ull; }
                    if (pm) { b7 = __ffsll(pm) - 1; pm &= pm - 1ull; }
                    int bg0 = (g == 0) ? b0 : (g == 1) ? b1 : (g == 2) ? b2 : b3;
                    int bg1 = (g == 0) ? b4 : (g == 1) ? b5 : (g == 2) ? b6 : b7;
                    ull rw0 = gmask[((c << 6) + bg0) * MASKW + w];  // independent
                    ull rw1 = gmask[((c << 6) + bg1) * MASKW + w];  // loads (dups ok)
                    supp0 |= rw0; supp1 |= rw1;
                }
                ull supp = supp0 | supp1;
                supp |= shflx64(supp, 16);            // OR across the 4 lane-groups
                supp |= shflx64(supp, 32);
                alive &= ~supp;                       // lanes 0-15 hold the words
            }
            if (lane == 0) s_ln = lnl;
        }
        __syncthreads();
        ln = s_ln;
    }

    bool need = (!pre_ok) || (ln < MAX_OUT);                  // uniform
    if (!need) {
        if (tid < 4 * MAX_OUT) {
            int q = tid >> 2;
            write_row_part(reg, anc, lnd, q, tid & 3, gidx[s_kept[q]], out);
        }
        return;
    }

    // ---- inline exact fallback: literal greedy over all N (round-10 validated) ----
    for (int i = tid; i < N_ANCHORS; i += BLK) {
        float sc = cls[i].y;
        sbuf[i] = ((double)sc > 0.4) ? sc : 0.0f;
    }
    __syncthreads();
    ln = 0;
    for (int oi = 0; oi < MAX_OUT; ++oi) {
        ull k = 0;
        for (int i = tid; i < N_ANCHORS; i += BLK) {
            ull kk = ((ull)__float_as_uint(sbuf[i]) << 32)
                   | (ull)(0xFFFFFFFFu - (unsigned int)i);
            if (kk > k) k = kk;
        }
        k = wmax(k);
        if ((tid & 63) == 0) warr[tid >> 6] = k;
        __syncthreads();
        if (tid < 64) {
            ull v = (tid < NW) ? warr[tid] : 0ull;
            v = wmax(v);
            if (tid == 0) s_win = v;
        }
        __syncthreads();
        ull win = s_win;
        if ((win >> 32) == 0u) break;
        int pidx = (int)(0xFFFFFFFFu - (unsigned int)win);
        if (tid == 0) {
            double b[4];
            decode_box_d(reg, anc, pidx, b);
            s_pb[0] = b[0]; s_pb[1] = b[1]; s_pb[2] = b[2]; s_pb[3] = b[3];
            s_pb[4] = (b[2] - b[0]) * (b[3] - b[1]);
            s_kept[oi] = pidx;                                // store IDX (fallback)
        }
        __syncthreads();
        double p0 = s_pb[0], p1 = s_pb[1], p2 = s_pb[2], p3 = s_pb[3], pa = s_pb[4];
        for (int i = tid; i < N_ANCHORS; i += BLK) {
            float v = sbuf[i];
            if (v != 0.0f) {
                double b[4];
                decode_box_d(reg, anc, i, b);
                double ih = fmin(b[2], p2) - fmax(b[0], p0); ih = fmax(ih, 0.0);
                double iw = fmin(b[3], p3) - fmax(b[1], p1); iw = fmax(iw, 0.0);
                double inter = ih * iw;
                double aa = (b[2] - b[0]) * (b[3] - b[1]);
                double den = aa + pa; den = den - inter; den = den + 1e-12;
                if (inter / den > 0.4) sbuf[i] = 0.0f;  // kills the pick too
            }
        }
        __syncthreads();
        ln = oi + 1;
    }
    __syncthreads();
    if (tid < 4 * MAX_OUT) {
        int q = tid >> 2;
        write_row_part(reg, anc, lnd, q, tid & 3, (q < ln) ? s_kept[q] : -1, out);
    }
}

extern "C" void kernel_launch(void* const* d_in, const int* in_sizes, int n_in,
                              void* d_out, int out_size, void* d_ws, size_t ws_size,
                              hipStream_t stream) {
    const float2* cls = (const float2*)d_in[0];    // (N,2) f32
    const float4* reg = (const float4*)d_in[1];    // (N,4) f32
    const float*  lnd = (const float*)d_in[2];     // (N,10) f32
    const float4* anc = (const float4*)d_in[3];    // (N,4) f32

    uint8_t* w = (uint8_t*)d_ws;
    int*    segcnt  = (int*)w;                  //      0: 672 B
    int*    meta    = (int*)(w + 768);          //    768: {ok, csel}
    ull*    segkeys = (ull*)(w + 1024);         //   1024: 168*32*8 = 43008 B
    // main-path scratch unions with fallback-only sbuf (total ws use: 732160 B)
    int*    gidx    = (int*)(w + 44032);        //  44032: 1024*4  = 4096 B
    float4* gbox    = (float4*)(w + 48128);     //  48128: 1024*16 = 16384 B
    ull*    gmask   = (ull*)(w + 64512);        //  64512: 1024*16*8 = 131072 B
    ull*    gdiag   = (ull*)(w + 195584);       // 195584: 1024*8 = 8192 B
    float*  sbuf    = (float*)(w + 44032);      //  44032: N*4 B (fallback only, aliases above)

    k_seg <<<GRID, BLK, 0, stream>>>(cls, segcnt, segkeys);
    k_rank<<<RGRID, RBLK, 0, stream>>>(reg, anc, segcnt, segkeys, meta, gidx, gbox);
    k_mask<<<MGRID, BLK, 0, stream>>>(meta, gbox, gmask, gdiag);
    k_pick<<<1, BLK, 0, stream>>>(cls, reg, anc, lnd, meta, gidx, gmask, gdiag,
                                  sbuf, (float*)d_out);
}

// Round 11
// 103.625 us; speedup vs baseline: 1.0262x; 1.0262x over previous
//
#include <hip/hip_runtime.h>
#include <stdint.h>

// Match numpy semantics: no FMA contraction anywhere in decision-critical math.
#pragma clang fp contract(off)

#define N_ANCHORS 172032  // compile-time problem constant
#define MAX_OUT 200
#define BLK 1024
#define GRID 168          // GRID*BLK == N_ANCHORS exactly
#define NW (BLK / 64)     // 16 waves
#define SEG 32            // per-block segment capacity (lambda~8.4 @VT=2.40; guarded)
#define NKEY (GRID * SEG) // 5376 — compact-key capacity
#define RMAX 1024         // suppression-matrix rank capacity. Correctness is
                          // guaranteed VT/RMAX-independent: if the true greedy's
                          // next pick lies outside the rank window, the windowed
                          // alive set is empty at that point -> ln<200 -> exact
                          // fallback. rank_200 < 900 (round-5 evidence) makes the
                          // fast path overwhelmingly likely.
#define MASKW (RMAX / 64) // 16 ull words per row
#define RCAND 64          // candidates ranked per k_rank block (emitted by wave 0)
#define RGRID (NKEY / RCAND) // 84 rank blocks (only ~csel/64 ~ 22 stay active)
#define RBLK 1024         // k_rank block size: 16 waves split the j-range
#define RW (RBLK / 64)    // 16 waves
#define MGRID 256         // k_mask blocks (4 IoU-words per wave — round-11 change)
#define VT 2.40f          // fixed prefix threshold: scores ~ N(0,1) =>
                          // csel ~ 1411 +/- 37 (>10 sigma above RMAX=1024, so
                          // top-1024-above-VT == top-1024-above-0.4).
                          // Inline exact fallback guards all tails.

typedef unsigned long long ull;
static_assert(GRID * BLK == N_ANCHORS, "grid covers anchors exactly");
static_assert(RMAX % 64 == 0, "mask words");
static_assert(RGRID * RCAND == NKEY, "rank grid covers key capacity");
static_assert(GRID <= 192, "prefix scan uses 3 waves");

// f64 decode: f32 inputs upcast to f64, reference op order. Returns (y1,x1,y2,x2).
__device__ __forceinline__ void decode_box_d(const float4* __restrict__ reg,
                                             const float4* __restrict__ anc, int i,
                                             double b[4]) {
#pragma clang fp contract(off)
    float4 r = reg[i];
    float4 a = anc[i];
    double dx = (double)r.x * 0.1;
    double dy = (double)r.y * 0.1;
    double dw = (double)r.z * 0.2;
    double dh = (double)r.w * 0.2;
    double xa = (double)a.x, ya = (double)a.y, wa = (double)a.z, ha = (double)a.w;
    double xc = dx * wa; xc = xc + xa;     // dx*w_a + x_a
    double yc = dy * ha; yc = yc + ya;     // dy*h_a + y_a
    double w = exp(dw) * wa;
    double h = exp(dh) * ha;
    double h2 = h * 0.5, w2 = w * 0.5;
    b[0] = yc - h2; b[1] = xc - w2; b[2] = yc + h2; b[3] = xc + w2;
}

// One quarter of an output row: part 0 = box float4; parts 1..3 = landmark pairs
// {0,1},{2,3},{4}. Arithmetic per field identical to prior validated write_row
// (rounds 4-10, absmax 0.0); split across 4 threads/row to cut the scattered-
// gather latency chain.
__device__ __forceinline__ void write_row_part(const float4* __restrict__ reg,
                                               const float4* __restrict__ anc,
                                               const float* __restrict__ lnd,
                                               int q, int part, int idx,
                                               float* __restrict__ out) {
#pragma clang fp contract(off)
    if (part == 0) {
        float4 bv = make_float4(0.f, 0.f, 0.f, 0.f);
        if (idx >= 0) {
            double bb[4];
            decode_box_d(reg, anc, idx, bb);
            bv = make_float4((float)bb[0], (float)bb[1], (float)bb[2], (float)bb[3]);
        }
        *(float4*)&out[q * 4] = bv;                        // 16B-aligned
        return;
    }
    int j0 = (part - 1) * 2;               // part 1 -> j0=0 (2 pairs); 2 -> 2; 3 -> 4 (1)
    int nj = (part == 3) ? 1 : 2;
    float2 lv[2] = {make_float2(0.f, 0.f), make_float2(0.f, 0.f)};
    if (idx >= 0) {
        float4 a = anc[idx];
        double xa = (double)a.x, ya = (double)a.y, wa = (double)a.z, ha = (double)a.w;
        const float2* l2p = (const float2*)lnd;            // (N,10) f32, 8B-aligned
        for (int k = 0; k < nj; ++k) {
            float2 lp = l2p[idx * 5 + j0 + k];
            double lx = (double)lp.x * 0.1;
            double ly = (double)lp.y * 0.1;
            lx = lx * wa; lx = lx + xa;
            ly = ly * ha; ly = ly + ya;
            lv[k] = make_float2((float)lx, (float)ly);
        }
    }
    float2* o2 = (float2*)&out[MAX_OUT * 4 + q * 10];      // 8B-aligned (800+10q even)
    for (int k = 0; k < nj; ++k) o2[j0 + k] = lv[k];
}

__device__ __forceinline__ ull wmax(ull k) {
    for (int d = 32; d > 0; d >>= 1) {
        ull o = __shfl_down(k, d, 64);
        if (o > k) k = o;
    }
    return k;
}

// uniform-lane 64-bit readlane (SGPR broadcast path — no ds_bpermute latency)
__device__ __forceinline__ ull readlane64(ull v, int l) {
    unsigned lo = (unsigned)__builtin_amdgcn_readlane((int)(unsigned)(v & 0xffffffffull), l);
    unsigned hi = (unsigned)__builtin_amdgcn_readlane((int)(unsigned)(v >> 32), l);
    return ((ull)hi << 32) | (ull)lo;
}

// 64-bit shfl_xor (two 32-bit halves)
__device__ __forceinline__ ull shflx64(ull v, int m) {
    int lo = __shfl_xor((int)(unsigned)(v & 0xffffffffull), m, 64);
    int hi = __shfl_xor((int)(unsigned)(v >> 32), m, 64);
    return ((ull)(unsigned)hi << 32) | (ull)(unsigned)lo;
}

// f64 IoU > 0.4 test, reference op order (validated in prior rounds).
__device__ __forceinline__ bool iou_gt_f4(float4 a, float4 p) {
#pragma clang fp contract(off)
    double y1 = (double)a.x, x1 = (double)a.y, y2 = (double)a.z, x2 = (double)a.w;
    double p0 = (double)p.x, p1 = (double)p.y, p2 = (double)p.z, p3 = (double)p.w;
    double ih = fmin(y2, p2) - fmax(y1, p0); ih = fmax(ih, 0.0);
    double iw = fmin(x2, p3) - fmax(x1, p1); iw = fmax(iw, 0.0);
    double inter = ih * iw;
    double aj = (y2 - y1) * (x2 - x1);
    double ap = (p2 - p0) * (p3 - p1);
    double den = aj + ap; den = den - inter; den = den + 1e-12;
    return (inter / den) > 0.4;
}

// ---------- kernel 1: segment compaction (no atomics, no memset needed) ----------
__global__ void __launch_bounds__(BLK) k_seg(const float2* __restrict__ cls,
                                             int* __restrict__ segcnt,
                                             ull* __restrict__ segkeys) {
    __shared__ int wcnt[NW];
    int tid = threadIdx.x, bid = blockIdx.x;
    int i = bid * BLK + tid;
    float sc = cls[i].y;                   // score = cls[:,1]
    bool c = (sc > VT);
    ull key = 0ull;
    if (c) key = ((ull)__float_as_uint(sc) << 32)
               | (ull)(0xFFFFFFFFu - (unsigned int)i);
    ull m = __ballot(c);
    int wid = tid >> 6, lane = tid & 63;
    if (lane == 0) wcnt[wid] = __popcll(m);
    __syncthreads();
    if (tid == 0) {
        int s = 0;
        for (int w = 0; w < NW; ++w) { int t = wcnt[w]; wcnt[w] = s; s += t; }
        segcnt[bid] = s;                   // unconditional (overflow detected downstream)
    }
    __syncthreads();
    if (c) {
        int pos = wcnt[wid] + __popcll(m & ((1ull << lane) - 1ull));
        if (pos < SEG) segkeys[bid * SEG + pos] = key;
    }
}

// emit one ranked candidate: idx + decoded box in rank order
__device__ __forceinline__ void rank_emit(const float4* __restrict__ reg,
                                          const float4* __restrict__ anc,
                                          int rank, ull key,
                                          int* __restrict__ gidx,
                                          float4* __restrict__ gbox) {
    int idx = (int)(0xFFFFFFFFu - (unsigned int)key);
    gidx[rank] = idx;
    double b[4];
    decode_box_d(reg, anc, idx, b);
    gbox[rank] = make_float4((float)b[0], (float)b[1], (float)b[2], (float)b[3]);
}

// ---------- kernel 2: PARALLEL rank-counting sort (84 blocks x 16 waves) ----------
// rank = #keys strictly greater (keys unique) => value-based, block order irrelevant.
// NOTE: candidate distribution across blocks is essential — per-block LDS
// broadcast reads scale as waves x csel; full-rank per block ~ csel^2/64 reads
// ~ 55us (round-1 evidence). Do not merge this into k_mask.
__global__ void __launch_bounds__(RBLK) k_rank(const float4* __restrict__ reg,
                                               const float4* __restrict__ anc,
                                               const int* __restrict__ segcnt,
                                               const ull* __restrict__ segkeys,
                                               int* __restrict__ meta,
                                               int* __restrict__ gidx,
                                               float4* __restrict__ gbox) {
    __shared__ ull skeys[NKEY];            // 43 KB
    __shared__ int scnt[GRID], spre[GRID];
    __shared__ int wsum[4];
    __shared__ ull wovf[4];
    __shared__ int spart[RBLK];            // per-wave partial ranks (4 KB)
    __shared__ int s_ok, s_csel;
    int tid = threadIdx.x, wid = tid >> 6, lane = tid & 63;

    // (a) parallel prefix over segment counts (GRID=168 -> waves 0..2)
    int v = 0; bool ovf = false;
    if (tid < GRID) { v = segcnt[tid]; scnt[tid] = v; ovf = (v > SEG); }
    int x = v;
    for (int d = 1; d < 64; d <<= 1) {
        int o = __shfl_up(x, d, 64);
        if (lane >= d) x += o;
    }
    ull om = __ballot(ovf);
    if (wid < 3 && lane == 63) { wsum[wid] = x; wovf[wid] = om; }
    __syncthreads();
    if (tid == 0) {
        int total = wsum[0] + wsum[1] + wsum[2];
        s_csel = total;
        s_ok = ((wovf[0] | wovf[1] | wovf[2]) == 0ull) ? 1 : 0;
        if (blockIdx.x == 0) { meta[0] = s_ok; meta[1] = total; }
    }
    __syncthreads();
    if (tid < GRID)
        spre[tid] = (x - v) + (wid >= 1 ? wsum[0] : 0) + (wid >= 2 ? wsum[1] : 0);
    bool okl = (s_ok != 0);
    int csel = s_csel;
    int cbase = blockIdx.x * RCAND;
    __syncthreads();                       // spre visible to all
    if (!okl) return;                      // uniform -> exact fallback in k_pick
    if (cbase >= csel) return;             // inactive tail blocks exit (uniform)

    // (b) stage dense keys (predicated scatter from padded segkeys)
    for (int t = tid; t < GRID * SEG; t += RBLK) {
        int s = t >> 5, k = t & (SEG - 1);
        if (k < scnt[s]) skeys[spre[s] + k] = segkeys[t];
    }
    __syncthreads();

    // (c) 16-wave partial rank counting (broadcast LDS reads, unroll 8)
    int per = (csel + RW - 1) / RW;
    int jb = wid * per;
    int je = jb + per; if (je > csel) je = csel;
    int c = cbase + lane;
    ull kc = (c < csel) ? skeys[c] : 0ull;
    int rk = 0;
#pragma unroll 8
    for (int j = jb; j < je; ++j)
        rk += (skeys[j] > kc) ? 1 : 0;
    spart[wid * 64 + lane] = rk;
    __syncthreads();

    // (d) wave 0: combine partials, emit rank-ordered idx + decoded box
    if (tid < RCAND) {
        int cc = cbase + tid;
        if (cc < csel) {
            int r = 0;
#pragma unroll
            for (int w = 0; w < RW; ++w) r += spart[w * 64 + tid];
            if (r < RMAX) rank_emit(reg, anc, r, skeys[cc], gidx, gbox);
        }
    }
}

// ---------- kernel 3: suppression bitmatrix (256 blocks, ballot form) ----------
// gmask[r*16+w] bit e <=> iou(box[w*64+e], box[r]) > 0.4. Diagonal bit naturally
// set => pick removes itself, preserving reference self-suppression semantics
// (incl. degenerate zero-area repeat picks). No atomics/fences: kernel-boundary
// ordering makes gmask visible to k_pick.
__global__ void __launch_bounds__(BLK) k_mask(const int* __restrict__ meta,
                                              const float4* __restrict__ gbox,
                                              ull* __restrict__ gmask) {
    __shared__ float4 cbox[RMAX];          // 16 KB
    if (meta[0] == 0) return;              // uniform
    int csel = meta[1];
    int rlim = csel < RMAX ? csel : RMAX;
    if (rlim <= 0) return;
    int tid = threadIdx.x, bid = blockIdx.x;
    int wid = tid >> 6, lane = tid & 63;
    for (int t = tid; t < rlim; t += BLK) cbox[t] = gbox[t];
    __syncthreads();
    int totw = rlim * MASKW;
    for (int w = bid * NW + wid; w < totw; w += MGRID * NW) {
        int row = w >> 4, word = w & (MASKW - 1);
        int col = (word << 6) + lane;
        bool hit = (col < rlim) && iou_gt_f4(cbox[col], cbox[row]);
        ull bits = __ballot(hit);
        if (lane == 0) gmask[w] = bits;
    }
}

// ---------- kernel 4: chunked register greedy + output (+inline exact fallback) ----
// (round-9 verbatim — measured best at 105.0 us)
__global__ void __launch_bounds__(BLK) k_pick(const float2* __restrict__ cls,
                                              const float4* __restrict__ reg,
                                              const float4* __restrict__ anc,
                                              const float* __restrict__ lnd,
                                              const int* __restrict__ meta,
                                              const int* __restrict__ gidx,
                                              const ull* __restrict__ gmask,
                                              float* __restrict__ sbuf,
                                              float* __restrict__ out) {
    __shared__ __align__(16) ull smask[RMAX * MASKW]; // 128 KB (160 KiB/WG available)
    __shared__ int s_kept[MAX_OUT];
    __shared__ int s_ln;
    __shared__ ull warr[NW];               // fallback
    __shared__ ull s_win;
    __shared__ double s_pb[5];

    int tid = threadIdx.x;
    int lane = tid & 63;
    bool pre_ok = (meta[0] != 0);
    int csel = meta[1];
    int rlim = csel < RMAX ? csel : RMAX;
    int ln = 0;

    if (pre_ok) {
        // vectorized 16B copy: rlim rows * 16 words = rlim*8 float4s
        int nv4 = rlim * (MASKW / 2);
        const float4* gm4 = (const float4*)gmask;
        float4* sm4 = (float4*)smask;
        for (int t = tid; t < nv4; t += BLK) sm4[t] = gm4[t];
        __syncthreads();
        // single-wave chunked greedy (rounds 7-9 validated):
        //  FIND: register-only greedy via the diag word,
        //  APPLY: 8 pick-rows per iteration (4 lane-groups x 2 independent
        //        ds_read_b64) OR-combined via shfl-xor -> one alive update.
        // Chunk-ascending + bit-ascending = rank-ascending: identical pick
        // sequence to the global lowest-alive-rank scan.
        if (tid < 64) {
            ull alive = 0ull;              // lane w owns rank word w (w < MASKW)
            if (lane < MASKW) {
                int lo = lane << 6;
                int n = rlim - lo;
                if (n >= 64) alive = ~0ull;
                else if (n > 0) alive = (1ull << n) - 1ull;
            }
            int lnl = 0;
            int nchunk = (rlim + 63) >> 6;
            int g = lane >> 4, w = lane & 15;
            for (int c = 0; c < nchunk && lnl < MAX_OUT; ++c) {
                ull aw = readlane64(alive, c);        // includes all prior suppression
                if (aw == 0ull) continue;
                int rowid = (c << 6) + lane;
                ull diag = (rowid < rlim) ? smask[rowid * MASKW + c] : 0ull;
                // FIND (registers only)
                ull cur = aw, pmask = 0ull;
                while (cur != 0ull && lnl < MAX_OUT) {
                    int b = __ffsll(cur) - 1;
                    if (lane == 0) s_kept[lnl] = (c << 6) + b;   // store RANK
                    lnl++;
                    pmask |= (1ull << b);
                    ull rowb = readlane64(diag, b);   // row b's intra-chunk bits
                    cur &= ~rowb;                     // self-bit naturally set (or not,
                                                      // for degenerate repeat picks)
                }
                if (lnl >= MAX_OUT) break;            // alive no longer needed
                // APPLY (8 rows in flight per iteration)
                ull pm = pmask;
                ull supp0 = 0ull, supp1 = 0ull;
                while (pm != 0ull) {
                    int b0 = __ffsll(pm) - 1; pm &= pm - 1ull;
                    int b1 = b0, b2 = b0, b3 = b0, b4 = b0, b5 = b0, b6 = b0, b7 = b0;
                    if (pm) { b1 = __ffsll(pm) - 1; pm &= pm - 1ull; }
                    if (pm) { b2 = __ffsll(pm) - 1; pm &= pm - 1ull; }
                    if (pm) { b3 = __ffsll(pm) - 1; pm &= pm - 1ull; }
                    if (pm) { b4 = __ffsll(pm) - 1; pm &= pm - 1ull; }
                    if (pm) { b5 = __ffsll(pm) - 1; pm &= pm - 1ull; }
                    if (pm) { b6 = __ffsll(pm) - 1; pm &= pm - 1ull; }
                    if (pm) { b7 = __ffsll(pm) - 1; pm &= pm - 1ull; }
                    int bg0 = (g == 0) ? b0 : (g == 1) ? b1 : (g == 2) ? b2 : b3;
                    int bg1 = (g == 0) ? b4 : (g == 1) ? b5 : (g == 2) ? b6 : b7;
                    ull rw0 = smask[((c << 6) + bg0) * MASKW + w];  // independent
                    ull rw1 = smask[((c << 6) + bg1) * MASKW + w];  // loads (dups ok)
                    supp0 |= rw0; supp1 |= rw1;
                }
                ull supp = supp0 | supp1;
                supp |= shflx64(supp, 16);            // OR across the 4 lane-groups
                supp |= shflx64(supp, 32);
                alive &= ~supp;                       // lanes 0-15 hold the words
            }
            if (lane == 0) s_ln = lnl;
        }
        __syncthreads();
        ln = s_ln;
    }

    bool need = (!pre_ok) || (ln < MAX_OUT);                  // uniform
    if (!need) {
        if (tid < 4 * MAX_OUT) {
            int q = tid >> 2;
            write_row_part(reg, anc, lnd, q, tid & 3, gidx[s_kept[q]], out);
        }
        return;
    }

    // ---- inline exact fallback: literal greedy over all N (round-10 validated) ----
    for (int i = tid; i < N_ANCHORS; i += BLK) {
        float sc = cls[i].y;
        sbuf[i] = ((double)sc > 0.4) ? sc : 0.0f;
    }
    __syncthreads();
    ln = 0;
    for (int oi = 0; oi < MAX_OUT; ++oi) {
        ull k = 0;
        for (int i = tid; i < N_ANCHORS; i += BLK) {
            ull kk = ((ull)__float_as_uint(sbuf[i]) << 32)
                   | (ull)(0xFFFFFFFFu - (unsigned int)i);
            if (kk > k) k = kk;
        }
        k = wmax(k);
        if ((tid & 63) == 0) warr[tid >> 6] = k;
        __syncthreads();
        if (tid < 64) {
            ull v = (tid < NW) ? warr[tid] : 0ull;
            v = wmax(v);
            if (tid == 0) s_win = v;
        }
        __syncthreads();
        ull win = s_win;
        if ((win >> 32) == 0u) break;
        int pidx = (int)(0xFFFFFFFFu - (unsigned int)win);
        if (tid == 0) {
            double b[4];
            decode_box_d(reg, anc, pidx, b);
            s_pb[0] = b[0]; s_pb[1] = b[1]; s_pb[2] = b[2]; s_pb[3] = b[3];
            s_pb[4] = (b[2] - b[0]) * (b[3] - b[1]);
            s_kept[oi] = pidx;                                // store IDX (fallback)
        }
        __syncthreads();
        double p0 = s_pb[0], p1 = s_pb[1], p2 = s_pb[2], p3 = s_pb[3], pa = s_pb[4];
        for (int i = tid; i < N_ANCHORS; i += BLK) {
            float v = sbuf[i];
            if (v != 0.0f) {
                double b[4];
                decode_box_d(reg, anc, i, b);
                double ih = fmin(b[2], p2) - fmax(b[0], p0); ih = fmax(ih, 0.0);
                double iw = fmin(b[3], p3) - fmax(b[1], p1); iw = fmax(iw, 0.0);
                double inter = ih * iw;
                double aa = (b[2] - b[0]) * (b[3] - b[1]);
                double den = aa + pa; den = den - inter; den = den + 1e-12;
                if (inter / den > 0.4) sbuf[i] = 0.0f;  // kills the pick too
            }
        }
        __syncthreads();
        ln = oi + 1;
    }
    __syncthreads();
    if (tid < 4 * MAX_OUT) {
        int q = tid >> 2;
        write_row_part(reg, anc, lnd, q, tid & 3, (q < ln) ? s_kept[q] : -1, out);
    }
}

extern "C" void kernel_launch(void* const* d_in, const int* in_sizes, int n_in,
                              void* d_out, int out_size, void* d_ws, size_t ws_size,
                              hipStream_t stream) {
    const float2* cls = (const float2*)d_in[0];    // (N,2) f32
    const float4* reg = (const float4*)d_in[1];    // (N,4) f32
    const float*  lnd = (const float*)d_in[2];     // (N,10) f32
    const float4* anc = (const float4*)d_in[3];    // (N,4) f32

    uint8_t* w = (uint8_t*)d_ws;
    int*    segcnt  = (int*)w;                  //      0: 672 B
    int*    meta    = (int*)(w + 768);          //    768: {ok, csel}
    ull*    segkeys = (ull*)(w + 1024);         //   1024: 168*32*8 = 43008 B
    // main-path scratch unions with fallback-only sbuf (total ws use: 732160 B)
    int*    gidx    = (int*)(w + 44032);        //  44032: 1024*4  = 4096 B
    float4* gbox    = (float4*)(w + 48128);     //  48128: 1024*16 = 16384 B
    ull*    gmask   = (ull*)(w + 64512);        //  64512: 1024*16*8 = 131072 B (16B-aligned)
    float*  sbuf    = (float*)(w + 44032);      //  44032: N*4 B (fallback only, aliases above)

    k_seg <<<GRID, BLK, 0, stream>>>(cls, segcnt, segkeys);
    k_rank<<<RGRID, RBLK, 0, stream>>>(reg, anc, segcnt, segkeys, meta, gidx, gbox);
    k_mask<<<MGRID, BLK, 0, stream>>>(meta, gbox, gmask);
    k_pick<<<1, BLK, 0, stream>>>(cls, reg, anc, lnd, meta, gidx, gmask, sbuf,
                                  (float*)d_out);
}